// Round 7
// baseline (780.012 us; speedup 1.0000x reference)
//
#include <hip/hip_runtime.h>

// s_gcn via bf16-split MFMA, two fused GEMM stages (R6 structure).
// R7: occupancy + pipeline.
//  - bias folded into a prepped bias2[c][w] table (init of stage-2 acc);
//    stage-1 acc starts at 0. Removes 24 always-live VGPRs.
//  - __launch_bounds__(512,4): force <=128 regs -> 4 waves/SIMD (was ~2).
//  - 2 barriers/subtile: Xt ds_write moved to loop top (WAR-safe after
//    the stage-2 barrier); x for ts+1 prefetched into registers right
//    after barrier A so HBM latency hides under stage-1 MFMA + H2 + stage-2.

typedef short short8 __attribute__((ext_vector_type(8)));
typedef float floatx4 __attribute__((ext_vector_type(4)));

#define K_NUM 3
#define C_IN  64
#define C_OUT 64
#define T_DIM 2048
#define V_DIM 25
#define N_DIM 16

#define TT    2                  // t per subtile
#define NSUB  16                 // subtiles per block
#define TWIN  (TT*NSUB)          // 32 t per block window
#define COLS  (TT*32)            // 64 padded cols

#define WBUF_ELEMS (12*4*64*8)   // [mt12][ks4][lane64][j8] u16
#define ABUF_OFF   49152         // bytes
#define ABUF_ELEMS (3*2*2*64*8)  // [k3][nt2][ks2][lane64][j8] u16
#define B2_OFF     (ABUF_OFF + ABUF_ELEMS*2)
#define B2_ELEMS   (4*2*64*4)    // [mt2_4][nt2][lane64][r4] f32

__device__ __forceinline__ unsigned short bf16_rne(float f) {
    unsigned int u = __builtin_bit_cast(unsigned int, f);
    unsigned int r = (u + 0x7FFFu + ((u >> 16) & 1u)) >> 16;
    return (unsigned short)r;
}
__device__ __forceinline__ float bf16_f32(unsigned short h) {
    return __builtin_bit_cast(float, (unsigned int)h << 16);
}
__device__ __forceinline__ int swzf(int row) { return (row & 7) ^ ((row >> 2) & 7); }

__global__ void sgcn_prep(const float* __restrict__ W, const float* __restrict__ A,
                          const float* __restrict__ b,
                          unsigned short* __restrict__ wbuf,
                          unsigned short* __restrict__ abuf,
                          float* __restrict__ b2buf) {
    int idx = blockIdx.x * 256 + threadIdx.x;
    if (idx < WBUF_ELEMS) {
        int j = idx & 7, lane = (idx >> 3) & 63, ks = (idx >> 9) & 3, mt = idx >> 11;
        int o  = mt * 16 + (lane & 15);
        int kk = ks * 32 + (lane >> 4) * 8 + j;
        int ci = kk >> 1;
        wbuf[idx] = bf16_rne(W[o * C_IN + ci]);
    }
    if (idx < ABUF_ELEMS) {
        int j = idx & 7, lane = (idx >> 3) & 63, ks = (idx >> 9) & 1, nt = (idx >> 10) & 1, k = idx >> 11;
        int w  = nt * 16 + (lane & 15);
        int kk = ks * 32 + (lane >> 4) * 8 + j;
        int v  = kk >> 1;
        float val = (v < V_DIM && w < V_DIM) ? A[(k * V_DIM + v) * V_DIM + w] : 0.f;
        abuf[idx] = bf16_rne(val);
    }
    if (idx < B2_ELEMS) {
        int r = idx & 3, lane = (idx >> 2) & 63, nt = (idx >> 8) & 1, mt2 = idx >> 9;
        int c = mt2 * 16 + (lane >> 4) * 4 + r;
        int w = nt * 16 + (lane & 15);
        float val = 0.f;
        if (w < V_DIM) {
            for (int k = 0; k < K_NUM; ++k) {
                float cs = 0.f;
                for (int v = 0; v < V_DIM; ++v) cs += A[(k * V_DIM + v) * V_DIM + w];
                val += b[k * C_OUT + c] * cs;
            }
        }
        b2buf[idx] = val;
    }
}

__global__ __launch_bounds__(512, 4)
void sgcn_main(const float* __restrict__ x,
               const unsigned short* __restrict__ wbuf,
               const unsigned short* __restrict__ abuf,
               const float* __restrict__ b2buf,
               float* __restrict__ out) {
    __shared__ unsigned short Xt[COLS * 128];           // 16 KB
    __shared__ unsigned short H2[K_NUM * TT * 64 * 64]; // 48 KB

    const int tid  = threadIdx.x;
    const int lane = tid & 63;
    const int wid  = tid >> 6;
    const int nb   = blockIdx.x >> 6;
    const int t_base = (blockIdx.x & 63) * TWIN;

    const int wm = wid & 1, wn = wid >> 1;   // stage-1: 2m x 4n
    const int mt2 = wid & 3, th = wid >> 2;  // stage-2: 4m x 2t

    // hoisted bias2 fragments (stage-2 acc init)
    floatx4 b2f[2];
    b2f[0] = reinterpret_cast<const floatx4*>(b2buf)[(mt2 * 2 + 0) * 64 + lane];
    b2f[1] = reinterpret_cast<const floatx4*>(b2buf)[(mt2 * 2 + 1) * 64 + lane];

    // zero never-written padded Xt cols (25..31, 57..63)
    for (int i = tid; i < 14 * 64; i += 512) {
        int pc = i >> 6, ci = i & 63;
        int col = (pc < 7) ? (25 + pc) : (50 + pc);
        ((unsigned int*)Xt)[(col * 64 + ci) ^ (swzf(col) * 4)] = 0u;
    }

    const int bcol = wn * 16 + (lane & 15);
    const int t_c  = bcol >> 5, v_c = bcol & 31;
    const int c_a  = mt2 * 16 + (lane & 15);

    // ---- x prefetch registers: up to 4 float2 per thread ----
    float2 xp[4];
    const float2* xbase = reinterpret_cast<const float2*>(
        x + ((size_t)nb * C_IN * T_DIM + t_base) * V_DIM);

    auto LOADX = [&](int ts) {
        const float2* xsrc = xbase + (size_t)ts * TT * V_DIM / 2;
        #pragma unroll
        for (int p = 0; p < 4; ++p) {
            int u = tid + p * 512;
            if (u < 1600)
                xp[p] = xsrc[(size_t)(u / 25) * (T_DIM * V_DIM / 2) + (u % 25)];
        }
    };
    auto WRITEX = [&]() {
        #pragma unroll
        for (int p = 0; p < 4; ++p) {
            int u = tid + p * 512;
            if (u < 1600) {
                int ci = u / 25, q = u % 25;
                #pragma unroll
                for (int e = 0; e < 2; ++e) {
                    int colg = 2 * q + e;
                    float f  = e ? xp[p].y : xp[p].x;
                    int col  = (colg >= 25) ? (colg + 7) : colg;
                    unsigned short hh = bf16_rne(f);
                    unsigned short hl = bf16_rne(f - bf16_f32(hh));
                    ((unsigned int*)Xt)[(col * 64 + ci) ^ (swzf(col) * 4)] =
                        (unsigned int)hh | ((unsigned int)hl << 16);
                }
            }
        }
    };

    LOADX(0);

    #pragma unroll 1
    for (int ts = 0; ts < NSUB; ++ts) {
        WRITEX();            // Xt(ts) from regs; WAR-safe vs stage-1(ts-1) reads
        __syncthreads();     // barrier A: Xt ready (and H2 reads of ts-1 done)

        // ---- stage-1: H = Wcat * Xcat (M=192 N=64 K=128) ----
        short8 bfr[4];
        #pragma unroll
        for (int ks = 0; ks < 4; ++ks)
            bfr[ks] = ((short8*)Xt)[(bcol * 16 + ks * 4 + (lane >> 4)) ^ swzf(bcol)];

        if (ts + 1 < NSUB) LOADX(ts + 1);   // issue next x loads early

        floatx4 acc1[6];
        #pragma unroll
        for (int im = 0; im < 6; ++im) acc1[im] = floatx4{0.f, 0.f, 0.f, 0.f};

        #pragma unroll
        for (int im = 0; im < 6; ++im) {
            int mt = wm * 6 + im;
            #pragma unroll
            for (int ks = 0; ks < 4; ++ks) {
                short8 afr = ((const short8*)wbuf)[(mt * 4 + ks) * 64 + lane];
                acc1[im] = __builtin_amdgcn_mfma_f32_16x16x32_bf16(afr, bfr[ks], acc1[im], 0, 0, 0);
            }
        }

        #pragma unroll
        for (int im = 0; im < 6; ++im) {
            int mt = wm * 6 + im;
            #pragma unroll
            for (int r = 0; r < 4; ++r) {
                int o = mt * 16 + (lane >> 4) * 4 + r;
                int k = o >> 6, c = o & 63;
                float h = acc1[im][r];
                unsigned short hh = bf16_rne(h);
                unsigned short hl = bf16_rne(h - bf16_f32(hh));
                int row = (k * TT + t_c) * 64 + c;
                ((unsigned int*)H2)[(row * 32 + v_c) ^ (swzf(c) * 4)] =
                    (unsigned int)hh | ((unsigned int)hl << 16);
            }
        }
        __syncthreads();     // barrier B: H2 ready

        // ---- stage-2: OUT = sum_k H_k * At_k (M=64 N=32 K=64) ----
        floatx4 acc2[2];
        acc2[0] = b2f[0];
        acc2[1] = b2f[1];
        #pragma unroll
        for (int k = 0; k < K_NUM; ++k) {
            short8 ha[2];
            int row = (k * TT + th) * 64 + c_a;
            #pragma unroll
            for (int ks = 0; ks < 2; ++ks)
                ha[ks] = ((short8*)H2)[(row * 8 + ks * 4 + (lane >> 4)) ^ swzf(c_a)];
            #pragma unroll
            for (int nt = 0; nt < 2; ++nt) {
                #pragma unroll
                for (int ks = 0; ks < 2; ++ks) {
                    short8 ab = ((const short8*)abuf)[((k * 2 + nt) * 2 + ks) * 64 + lane];
                    acc2[nt] = __builtin_amdgcn_mfma_f32_16x16x32_bf16(ha[ks], ab, acc2[nt], 0, 0, 0);
                }
            }
        }

        const int tg = t_base + ts * TT + th;
        const int c0 = mt2 * 16 + (lane >> 4) * 4;
        const int wl = lane & 15;
        #pragma unroll
        for (int r = 0; r < 4; ++r)
            out[((size_t)(nb * C_OUT + c0 + r) * T_DIM + tg) * V_DIM + wl] = acc2[0][r];
        if (wl < 9) {
            #pragma unroll
            for (int r = 0; r < 4; ++r)
                out[((size_t)(nb * C_OUT + c0 + r) * T_DIM + tg) * V_DIM + 16 + wl] = acc2[1][r];
        }
        // no barrier here: next iter's WRITEX touches Xt only, and next
        // stage-1's H2 writes are fenced by barrier A.
    }
}

extern "C" void kernel_launch(void* const* d_in, const int* in_sizes, int n_in,
                              void* d_out, int out_size, void* d_ws, size_t ws_size,
                              hipStream_t stream) {
    const float* x = (const float*)d_in[0];
    const float* A = (const float*)d_in[1];
    const float* W = (const float*)d_in[2];
    const float* b = (const float*)d_in[3];
    float* out = (float*)d_out;

    unsigned short* wbuf = (unsigned short*)d_ws;
    unsigned short* abuf = (unsigned short*)((char*)d_ws + ABUF_OFF);
    float* b2buf = (float*)((char*)d_ws + B2_OFF);

    sgcn_prep<<<(WBUF_ELEMS + 255) / 256, 256, 0, stream>>>(W, A, b, wbuf, abuf, b2buf);

    dim3 grid(N_DIM * (T_DIM / TWIN));   // 1024 blocks
    sgcn_main<<<grid, 512, 0, stream>>>(x, wbuf, abuf, b2buf, out);
}

// Round 8
// 162.957 us; speedup vs baseline: 4.7866x; 4.7866x over previous
//
#include <hip/hip_runtime.h>

// s_gcn via bf16-split MFMA, two fused GEMM stages (R6 structure).
// R7: bias folded into prepped bias2 table; 2 barriers/subtile; reg x-prefetch.
// R8: REVERT launch_bounds(512,4) -> (512). The ,4 capped VGPR at 64 and
//     spilled ~50 regs to scratch: FETCH 103MB->2.06GB, dur 304->855us.
//     Spill-free beats occupancy here (Guideline 6).

typedef short short8 __attribute__((ext_vector_type(8)));
typedef float floatx4 __attribute__((ext_vector_type(4)));

#define K_NUM 3
#define C_IN  64
#define C_OUT 64
#define T_DIM 2048
#define V_DIM 25
#define N_DIM 16

#define TT    2                  // t per subtile
#define NSUB  16                 // subtiles per block
#define TWIN  (TT*NSUB)          // 32 t per block window
#define COLS  (TT*32)            // 64 padded cols

#define WBUF_ELEMS (12*4*64*8)   // [mt12][ks4][lane64][j8] u16
#define ABUF_OFF   49152         // bytes
#define ABUF_ELEMS (3*2*2*64*8)  // [k3][nt2][ks2][lane64][j8] u16
#define B2_OFF     (ABUF_OFF + ABUF_ELEMS*2)
#define B2_ELEMS   (4*2*64*4)    // [mt2_4][nt2][lane64][r4] f32

__device__ __forceinline__ unsigned short bf16_rne(float f) {
    unsigned int u = __builtin_bit_cast(unsigned int, f);
    unsigned int r = (u + 0x7FFFu + ((u >> 16) & 1u)) >> 16;
    return (unsigned short)r;
}
__device__ __forceinline__ float bf16_f32(unsigned short h) {
    return __builtin_bit_cast(float, (unsigned int)h << 16);
}
__device__ __forceinline__ int swzf(int row) { return (row & 7) ^ ((row >> 2) & 7); }

__global__ void sgcn_prep(const float* __restrict__ W, const float* __restrict__ A,
                          const float* __restrict__ b,
                          unsigned short* __restrict__ wbuf,
                          unsigned short* __restrict__ abuf,
                          float* __restrict__ b2buf) {
    int idx = blockIdx.x * 256 + threadIdx.x;
    if (idx < WBUF_ELEMS) {
        int j = idx & 7, lane = (idx >> 3) & 63, ks = (idx >> 9) & 3, mt = idx >> 11;
        int o  = mt * 16 + (lane & 15);
        int kk = ks * 32 + (lane >> 4) * 8 + j;
        int ci = kk >> 1;
        wbuf[idx] = bf16_rne(W[o * C_IN + ci]);
    }
    if (idx < ABUF_ELEMS) {
        int j = idx & 7, lane = (idx >> 3) & 63, ks = (idx >> 9) & 1, nt = (idx >> 10) & 1, k = idx >> 11;
        int w  = nt * 16 + (lane & 15);
        int kk = ks * 32 + (lane >> 4) * 8 + j;
        int v  = kk >> 1;
        float val = (v < V_DIM && w < V_DIM) ? A[(k * V_DIM + v) * V_DIM + w] : 0.f;
        abuf[idx] = bf16_rne(val);
    }
    if (idx < B2_ELEMS) {
        int r = idx & 3, lane = (idx >> 2) & 63, nt = (idx >> 8) & 1, mt2 = idx >> 9;
        int c = mt2 * 16 + (lane >> 4) * 4 + r;
        int w = nt * 16 + (lane & 15);
        float val = 0.f;
        if (w < V_DIM) {
            for (int k = 0; k < K_NUM; ++k) {
                float cs = 0.f;
                for (int v = 0; v < V_DIM; ++v) cs += A[(k * V_DIM + v) * V_DIM + w];
                val += b[k * C_OUT + c] * cs;
            }
        }
        b2buf[idx] = val;
    }
}

__global__ __launch_bounds__(512)
void sgcn_main(const float* __restrict__ x,
               const unsigned short* __restrict__ wbuf,
               const unsigned short* __restrict__ abuf,
               const float* __restrict__ b2buf,
               float* __restrict__ out) {
    __shared__ unsigned short Xt[COLS * 128];           // 16 KB
    __shared__ unsigned short H2[K_NUM * TT * 64 * 64]; // 48 KB

    const int tid  = threadIdx.x;
    const int lane = tid & 63;
    const int wid  = tid >> 6;
    const int nb   = blockIdx.x >> 6;
    const int t_base = (blockIdx.x & 63) * TWIN;

    const int wm = wid & 1, wn = wid >> 1;   // stage-1: 2m x 4n
    const int mt2 = wid & 3, th = wid >> 2;  // stage-2: 4m x 2t

    // hoisted bias2 fragments (stage-2 acc init)
    floatx4 b2f[2];
    b2f[0] = reinterpret_cast<const floatx4*>(b2buf)[(mt2 * 2 + 0) * 64 + lane];
    b2f[1] = reinterpret_cast<const floatx4*>(b2buf)[(mt2 * 2 + 1) * 64 + lane];

    // zero never-written padded Xt cols (25..31, 57..63)
    for (int i = tid; i < 14 * 64; i += 512) {
        int pc = i >> 6, ci = i & 63;
        int col = (pc < 7) ? (25 + pc) : (50 + pc);
        ((unsigned int*)Xt)[(col * 64 + ci) ^ (swzf(col) * 4)] = 0u;
    }

    const int bcol = wn * 16 + (lane & 15);
    const int t_c  = bcol >> 5, v_c = bcol & 31;
    const int c_a  = mt2 * 16 + (lane & 15);

    // ---- x prefetch registers: up to 4 float2 per thread ----
    float2 xp[4];
    const float2* xbase = reinterpret_cast<const float2*>(
        x + ((size_t)nb * C_IN * T_DIM + t_base) * V_DIM);

    auto LOADX = [&](int ts) {
        const float2* xsrc = xbase + (size_t)ts * TT * V_DIM / 2;
        #pragma unroll
        for (int p = 0; p < 4; ++p) {
            int u = tid + p * 512;
            if (u < 1600)
                xp[p] = xsrc[(size_t)(u / 25) * (T_DIM * V_DIM / 2) + (u % 25)];
        }
    };
    auto WRITEX = [&]() {
        #pragma unroll
        for (int p = 0; p < 4; ++p) {
            int u = tid + p * 512;
            if (u < 1600) {
                int ci = u / 25, q = u % 25;
                #pragma unroll
                for (int e = 0; e < 2; ++e) {
                    int colg = 2 * q + e;
                    float f  = e ? xp[p].y : xp[p].x;
                    int col  = (colg >= 25) ? (colg + 7) : colg;
                    unsigned short hh = bf16_rne(f);
                    unsigned short hl = bf16_rne(f - bf16_f32(hh));
                    ((unsigned int*)Xt)[(col * 64 + ci) ^ (swzf(col) * 4)] =
                        (unsigned int)hh | ((unsigned int)hl << 16);
                }
            }
        }
    };

    LOADX(0);

    #pragma unroll 1
    for (int ts = 0; ts < NSUB; ++ts) {
        WRITEX();            // Xt(ts) from regs; WAR-safe vs stage-1(ts-1) reads
        __syncthreads();     // barrier A: Xt ready (and H2 reads of ts-1 done)

        // ---- stage-1: H = Wcat * Xcat (M=192 N=64 K=128) ----
        short8 bfr[4];
        #pragma unroll
        for (int ks = 0; ks < 4; ++ks)
            bfr[ks] = ((short8*)Xt)[(bcol * 16 + ks * 4 + (lane >> 4)) ^ swzf(bcol)];

        if (ts + 1 < NSUB) LOADX(ts + 1);   // issue next x loads early

        floatx4 acc1[6];
        #pragma unroll
        for (int im = 0; im < 6; ++im) acc1[im] = floatx4{0.f, 0.f, 0.f, 0.f};

        #pragma unroll
        for (int im = 0; im < 6; ++im) {
            int mt = wm * 6 + im;
            #pragma unroll
            for (int ks = 0; ks < 4; ++ks) {
                short8 afr = ((const short8*)wbuf)[(mt * 4 + ks) * 64 + lane];
                acc1[im] = __builtin_amdgcn_mfma_f32_16x16x32_bf16(afr, bfr[ks], acc1[im], 0, 0, 0);
            }
        }

        #pragma unroll
        for (int im = 0; im < 6; ++im) {
            int mt = wm * 6 + im;
            #pragma unroll
            for (int r = 0; r < 4; ++r) {
                int o = mt * 16 + (lane >> 4) * 4 + r;
                int k = o >> 6, c = o & 63;
                float h = acc1[im][r];
                unsigned short hh = bf16_rne(h);
                unsigned short hl = bf16_rne(h - bf16_f32(hh));
                int row = (k * TT + t_c) * 64 + c;
                ((unsigned int*)H2)[(row * 32 + v_c) ^ (swzf(c) * 4)] =
                    (unsigned int)hh | ((unsigned int)hl << 16);
            }
        }
        __syncthreads();     // barrier B: H2 ready

        // ---- stage-2: OUT = sum_k H_k * At_k (M=64 N=32 K=64) ----
        floatx4 acc2[2];
        acc2[0] = b2f[0];
        acc2[1] = b2f[1];
        #pragma unroll
        for (int k = 0; k < K_NUM; ++k) {
            short8 ha[2];
            int row = (k * TT + th) * 64 + c_a;
            #pragma unroll
            for (int ks = 0; ks < 2; ++ks)
                ha[ks] = ((short8*)H2)[(row * 8 + ks * 4 + (lane >> 4)) ^ swzf(c_a)];
            #pragma unroll
            for (int nt = 0; nt < 2; ++nt) {
                #pragma unroll
                for (int ks = 0; ks < 2; ++ks) {
                    short8 ab = ((const short8*)abuf)[((k * 2 + nt) * 2 + ks) * 64 + lane];
                    acc2[nt] = __builtin_amdgcn_mfma_f32_16x16x32_bf16(ha[ks], ab, acc2[nt], 0, 0, 0);
                }
            }
        }

        const int tg = t_base + ts * TT + th;
        const int c0 = mt2 * 16 + (lane >> 4) * 4;
        const int wl = lane & 15;
        #pragma unroll
        for (int r = 0; r < 4; ++r)
            out[((size_t)(nb * C_OUT + c0 + r) * T_DIM + tg) * V_DIM + wl] = acc2[0][r];
        if (wl < 9) {
            #pragma unroll
            for (int r = 0; r < 4; ++r)
                out[((size_t)(nb * C_OUT + c0 + r) * T_DIM + tg) * V_DIM + 16 + wl] = acc2[1][r];
        }
        // no barrier here: next iter's WRITEX touches Xt only; next stage-1's
        // H2 writes are fenced by barrier A.
    }
}

extern "C" void kernel_launch(void* const* d_in, const int* in_sizes, int n_in,
                              void* d_out, int out_size, void* d_ws, size_t ws_size,
                              hipStream_t stream) {
    const float* x = (const float*)d_in[0];
    const float* A = (const float*)d_in[1];
    const float* W = (const float*)d_in[2];
    const float* b = (const float*)d_in[3];
    float* out = (float*)d_out;

    unsigned short* wbuf = (unsigned short*)d_ws;
    unsigned short* abuf = (unsigned short*)((char*)d_ws + ABUF_OFF);
    float* b2buf = (float*)((char*)d_ws + B2_OFF);

    sgcn_prep<<<(WBUF_ELEMS + 255) / 256, 256, 0, stream>>>(W, A, b, wbuf, abuf, b2buf);

    dim3 grid(N_DIM * (T_DIM / TWIN));   // 1024 blocks
    sgcn_main<<<grid, 512, 0, stream>>>(x, wbuf, abuf, b2buf, out);
}